// Round 16
// baseline (280.888 us; speedup 1.0000x reference)
//
#include <hip/hip_runtime.h>
#include <stdint.h>

#define N_NODES 50000
#define M_EDGES 25000
#define NNZF    800000
#define F_IN    128
#define HID     256
#define F_OUT   128

#define CAP_N 64    // max node degree slot (Poisson(16): P>=64 ~ 1e-19/node)
#define CAP_E 96    // max edge cardinality slot (Poisson(32): negligible)

typedef __attribute__((ext_vector_type(8))) short bf16x8;
typedef __attribute__((ext_vector_type(4))) float f32x4;

__device__ __forceinline__ unsigned short bf16_rne(float f) {
    uint32_t b = __float_as_uint(f);
    b += 0x7FFF + ((b >> 16) & 1);
    return (unsigned short)(b >> 16);
}
__device__ __forceinline__ float bf16f(unsigned short h) {
    return __uint_as_float(((uint32_t)h) << 16);
}
__device__ __forceinline__ float bflo(unsigned u) { return __uint_as_float(u << 16); }
__device__ __forceinline__ float bfhi(unsigned u) { return __uint_as_float(u & 0xffff0000u); }

// ---------------- fp32 -> bf16 row conversion (x only) ----------------
__global__ void f32_to_bf16(const float* __restrict__ in, unsigned short* __restrict__ outp, int n) {
    int i = (blockIdx.x * blockDim.x + threadIdx.x) * 8;
    if (i >= n) return;
    float4 v0 = *reinterpret_cast<const float4*>(in + i);
    float4 v1 = *reinterpret_cast<const float4*>(in + i + 4);
    ushort4 o0, o1;
    o0.x = bf16_rne(v0.x); o0.y = bf16_rne(v0.y); o0.z = bf16_rne(v0.z); o0.w = bf16_rne(v0.w);
    o1.x = bf16_rne(v1.x); o1.y = bf16_rne(v1.y); o1.z = bf16_rne(v1.z); o1.w = bf16_rne(v1.w);
    *reinterpret_cast<ushort4*>(outp + i)     = o0;
    *reinterpret_cast<ushort4*>(outp + i + 4) = o1;
}

// ---------------- padded-CSR fill, XCD-binned + 4-entry/thread atomic pipeline ----------------
// Same layout/semantics as R14's fill, but each thread owns 4 consecutive entries:
// all (<=8) predicated atomics issue back-to-back before any dependent store, giving an
// 8-deep atomic pipeline per wave instead of 2-deep (atomic latency hiding via ILP).
__global__ __launch_bounds__(256) void fill_pad_ilp(
    const int* __restrict__ nidx, const int* __restrict__ eidx,
    int* __restrict__ cntN, int* __restrict__ cntE,
    int* __restrict__ listN, int* __restrict__ listE, int nnz) {
    int p = blockIdx.x & 7;
    int blk = blockIdx.x >> 3;
    int i = (blk * 256 + threadIdx.x) * 4;
    if (i >= nnz) return;
    int4 a = *reinterpret_cast<const int4*>(nidx + i);
    int4 b = *reinterpret_cast<const int4*>(eidx + i);
    int nd0 = a.x, nd1 = a.y, nd2 = a.z, nd3 = a.w;
    int ed0 = b.x, ed1 = b.y, ed2 = b.z, ed3 = b.w;

    int sE0 = (ed0 / 3125 == p) ? atomicAdd(cntE + ed0, 1) : -1;
    int sE1 = (ed1 / 3125 == p) ? atomicAdd(cntE + ed1, 1) : -1;
    int sE2 = (ed2 / 3125 == p) ? atomicAdd(cntE + ed2, 1) : -1;
    int sE3 = (ed3 / 3125 == p) ? atomicAdd(cntE + ed3, 1) : -1;
    int sN0 = (nd0 / 6250 == p) ? atomicAdd(cntN + nd0, 1) : -1;
    int sN1 = (nd1 / 6250 == p) ? atomicAdd(cntN + nd1, 1) : -1;
    int sN2 = (nd2 / 6250 == p) ? atomicAdd(cntN + nd2, 1) : -1;
    int sN3 = (nd3 / 6250 == p) ? atomicAdd(cntN + nd3, 1) : -1;

    if (sE0 >= 0 && sE0 < CAP_E) listE[ed0 * CAP_E + sE0] = nd0;
    if (sE1 >= 0 && sE1 < CAP_E) listE[ed1 * CAP_E + sE1] = nd1;
    if (sE2 >= 0 && sE2 < CAP_E) listE[ed2 * CAP_E + sE2] = nd2;
    if (sE3 >= 0 && sE3 < CAP_E) listE[ed3 * CAP_E + sE3] = nd3;
    if (sN0 >= 0 && sN0 < CAP_N) listN[nd0 * CAP_N + sN0] = ed0;
    if (sN1 >= 0 && sN1 < CAP_N) listN[nd1 * CAP_N + sN1] = ed1;
    if (sN2 >= 0 && sN2 < CAP_N) listN[nd2 * CAP_N + sN2] = ed2;
    if (sN3 >= 0 && sN3 < CAP_N) listN[nd3 * CAP_N + sN3] = ed3;
}

// ---------------- inverse degree from counts ----------------
__global__ void inv_cnt2(const int* __restrict__ cntN, float* __restrict__ invN,
                         const int* __restrict__ cntE, float* __restrict__ invE) {
    int i = blockIdx.x * blockDim.x + threadIdx.x;
    if (i < N_NODES) { int v = cntN[i]; invN[i] = (v > 0) ? 1.0f / (float)v : 0.0f; }
    if (i < M_EDGES) { int v = cntE[i]; invE[i] = (v > 0) ? 1.0f / (float)v : 0.0f; }
}

// ---------------- gather segment-sum of 128-wide bf16 rows ----------------
// OUTMODE: 0 = bf16 only, 1 = fp32 only, 2 = both.
template<bool SCALE_DST, bool ADD_BIAS, int OUTMODE, int CAP>
__global__ __launch_bounds__(256) void gather_bf(
    const unsigned short* __restrict__ src, const int* __restrict__ cnt,
    const int* __restrict__ list, const float* __restrict__ dstscale,
    const float* __restrict__ bias,
    unsigned short* __restrict__ dstb, float* __restrict__ dstf, int rows) {
    int row = blockIdx.x * 4 + (threadIdx.x >> 6);
    if (row >= rows) return;
    int lane = threadIdx.x & 63;
    int half = lane >> 5;
    int l32 = lane & 31;
    const unsigned short* sp = src + l32 * 4;
    int c = cnt[row]; if (c > CAP) c = CAP;
    int s0 = row * CAP, s1 = s0 + c;

    float a0 = 0.f, a1 = 0.f, a2 = 0.f, a3 = 0.f;
    float c0 = 0.f, c1 = 0.f, c2 = 0.f, c3 = 0.f;
    int j = s0 + half;
    for (; j + 2 < s1; j += 4) {
        int i0 = list[j];
        int i1 = list[j + 2];
        uint2 u = *reinterpret_cast<const uint2*>(sp + (int64_t)i0 * 128);
        uint2 v = *reinterpret_cast<const uint2*>(sp + (int64_t)i1 * 128);
        a0 += bflo(u.x); a1 += bfhi(u.x); a2 += bflo(u.y); a3 += bfhi(u.y);
        c0 += bflo(v.x); c1 += bfhi(v.x); c2 += bflo(v.y); c3 += bfhi(v.y);
    }
    for (; j < s1; j += 2) {
        int i0 = list[j];
        uint2 u = *reinterpret_cast<const uint2*>(sp + (int64_t)i0 * 128);
        a0 += bflo(u.x); a1 += bfhi(u.x); a2 += bflo(u.y); a3 += bfhi(u.y);
    }
    a0 += c0; a1 += c1; a2 += c2; a3 += c3;

    a0 += __shfl_down(a0, 32, 64);
    a1 += __shfl_down(a1, 32, 64);
    a2 += __shfl_down(a2, 32, 64);
    a3 += __shfl_down(a3, 32, 64);

    if (half == 0) {
        if (SCALE_DST) {
            float sc = dstscale[row];
            a0 *= sc; a1 *= sc; a2 *= sc; a3 *= sc;
        }
        if (ADD_BIAS) {
            float4 bv = *reinterpret_cast<const float4*>(bias + l32 * 4);
            a0 += bv.x; a1 += bv.y; a2 += bv.z; a3 += bv.w;
        }
        if (OUTMODE == 1 || OUTMODE == 2) {
            float4 o; o.x = a0; o.y = a1; o.z = a2; o.w = a3;
            *reinterpret_cast<float4*>(dstf + (int64_t)row * 128 + l32 * 4) = o;
        }
        if (OUTMODE == 0 || OUTMODE == 2) {
            ushort4 ob;
            ob.x = bf16_rne(a0); ob.y = bf16_rne(a1);
            ob.z = bf16_rne(a2); ob.w = bf16_rne(a3);
            *reinterpret_cast<ushort4*>(dstb + (int64_t)row * 128 + l32 * 4) = ob;
        }
    }
}

// ---------------- pack W[K x Nc] into MFMA-fragment-ordered bf16 hi/lo ----------------
__global__ void pack_w(const float* __restrict__ W, short* __restrict__ Ph,
                       short* __restrict__ Pl, int K, int Nc) {
    int i = blockIdx.x * blockDim.x + threadIdx.x;
    if (i >= K * Nc) return;
    int k = i / Nc, n = i % Nc;
    float v = W[i];
    unsigned short h = bf16_rne(v);
    unsigned short lo = bf16_rne(v - bf16f(h));
    int KCH = K >> 5;
    int jt = n >> 4, c = k >> 5;
    int lane = (n & 15) | (((k >> 3) & 3) << 4);
    int j = k & 7;
    int64_t off = (((int64_t)(jt * KCH + c)) * 64 + lane) * 8 + j;
    Ph[off] = (short)h;
    Pl[off] = (short)lo;
}

// ---------------- FUSED MLP: hp = (elu(z@W1+b1)) @ W2, all bf16, h via per-wave LDS ----------------
__global__ __launch_bounds__(256) void gemm_fused(
    const unsigned short* __restrict__ A,
    const short* __restrict__ P1h, const short* __restrict__ P1l,
    const float* __restrict__ b1,
    const short* __restrict__ P2h, const short* __restrict__ P2l,
    unsigned short* __restrict__ Cout, int Mr) {
    __shared__ unsigned short ht[4][16][264];   // 33792 B
    int wid = threadIdx.x >> 6;
    int strip = blockIdx.x * 4 + wid;
    if (strip * 16 >= Mr) return;
    int l = threadIdx.x & 63;
    int lr = l & 15, lq = l >> 4;
    int arow = strip * 16 + lr;

    bf16x8 a1[4];
    const unsigned short* ap = A + (int64_t)arow * F_IN + lq * 8;
    #pragma unroll
    for (int c = 0; c < 4; ++c)
        a1[c] = *reinterpret_cast<const bf16x8*>(ap + c * 32);

    #pragma unroll
    for (int jt = 0; jt < HID / 16; ++jt) {
        f32x4 acc = {0.f, 0.f, 0.f, 0.f};
        #pragma unroll
        for (int c = 0; c < 4; ++c) {
            int64_t off = (((int64_t)(jt * 4 + c)) * 64 + l) * 8;
            bf16x8 bh = *reinterpret_cast<const bf16x8*>(P1h + off);
            bf16x8 bl = *reinterpret_cast<const bf16x8*>(P1l + off);
            acc = __builtin_amdgcn_mfma_f32_16x16x32_bf16(a1[c], bh, acc, 0, 0, 0);
            acc = __builtin_amdgcn_mfma_f32_16x16x32_bf16(a1[c], bl, acc, 0, 0, 0);
        }
        int col = jt * 16 + lr;
        float bv = b1[col];
        #pragma unroll
        for (int j = 0; j < 4; ++j) {
            float v = acc[j] + bv;
            v = (v > 0.f) ? v : expm1f(v);
            ht[wid][lq * 4 + j][col] = bf16_rne(v);
        }
    }

    bf16x8 a2[8];
    #pragma unroll
    for (int c = 0; c < 8; ++c)
        a2[c] = *reinterpret_cast<const bf16x8*>(&ht[wid][lr][lq * 8 + c * 32]);

    #pragma unroll
    for (int jt = 0; jt < F_OUT / 16; ++jt) {
        f32x4 acc = {0.f, 0.f, 0.f, 0.f};
        #pragma unroll
        for (int c = 0; c < 8; ++c) {
            int64_t off = (((int64_t)(jt * 8 + c)) * 64 + l) * 8;
            bf16x8 bh = *reinterpret_cast<const bf16x8*>(P2h + off);
            bf16x8 bl = *reinterpret_cast<const bf16x8*>(P2l + off);
            acc = __builtin_amdgcn_mfma_f32_16x16x32_bf16(a2[c], bh, acc, 0, 0, 0);
            acc = __builtin_amdgcn_mfma_f32_16x16x32_bf16(a2[c], bl, acc, 0, 0, 0);
        }
        int col = jt * 16 + lr;
        #pragma unroll
        for (int j = 0; j < 4; ++j)
            Cout[(int64_t)(strip * 16 + lq * 4 + j) * F_OUT + col] = bf16_rne(acc[j]);
    }
}

// ---------------- launch ----------------
extern "C" void kernel_launch(void* const* d_in, const int* in_sizes, int n_in,
                              void* d_out, int out_size, void* d_ws, size_t ws_size,
                              hipStream_t stream) {
    const float* x   = (const float*)d_in[0];
    const float* W1  = (const float*)d_in[1];
    const float* b1  = (const float*)d_in[2];
    const float* W2  = (const float*)d_in[3];
    const float* b2  = (const float*)d_in[4];
    const int*   nidx = (const int*)d_in[5];
    const int*   eidx = (const int*)d_in[6];

    float* out   = (float*)d_out;                      // [N, 128] fp32
    float* e_out = out + (size_t)N_NODES * F_OUT;      // [M, 128] fp32

    char* ws = (char*)d_ws;
    size_t off = 0;
    auto alloc = [&](size_t bytes) -> void* {
        void* p = ws + off;
        off += (bytes + 511) & ~(size_t)511;
        return p;
    };
    int* cntN    = (int*)alloc((size_t)(N_NODES + M_EDGES) * 4);   // contiguous; fill cursors == counts
    int* cntE    = cntN + N_NODES;
    float* Dinv  = (float*)alloc((size_t)N_NODES * 4);
    float* Binv  = (float*)alloc((size_t)M_EDGES * 4);
    int* listN   = (int*)alloc((size_t)N_NODES * CAP_N * 4);
    int* listE   = (int*)alloc((size_t)M_EDGES * CAP_E * 4);
    unsigned short* xb  = (unsigned short*)alloc((size_t)N_NODES * F_IN * 2);
    unsigned short* y   = (unsigned short*)alloc((size_t)M_EDGES * F_IN * 2);  // also ebf
    unsigned short* z   = (unsigned short*)alloc((size_t)N_NODES * F_IN * 2);  // also hp (in-place)
    short* pb1h  = (short*)alloc((size_t)F_IN * HID * 2);
    short* pb1l  = (short*)alloc((size_t)F_IN * HID * 2);
    short* pb2h  = (short*)alloc((size_t)HID * F_OUT * 2);
    short* pb2l  = (short*)alloc((size_t)HID * F_OUT * 2);

    hipMemsetAsync(cntN, 0, (size_t)(N_NODES + M_EDGES) * 4, stream);

    f32_to_bf16<<<(N_NODES * F_IN / 8 + 255) / 256, 256, 0, stream>>>(x, xb, N_NODES * F_IN);
    pack_w<<<(F_IN * HID + 255) / 256, 256, 0, stream>>>(W1, pb1h, pb1l, F_IN, HID);
    pack_w<<<(HID * F_OUT + 255) / 256, 256, 0, stream>>>(W2, pb2h, pb2l, HID, F_OUT);

    {
        int nthreads_per_pass = NNZF / 4;              // 200000 (4 entries/thread)
        int nblk_per_pass = (nthreads_per_pass + 255) / 256;   // 782
        fill_pad_ilp<<<nblk_per_pass * 8, 256, 0, stream>>>(
            nidx, eidx, cntN, cntE, listN, listE, NNZF);
    }
    inv_cnt2<<<(N_NODES + 255) / 256, 256, 0, stream>>>(cntN, Dinv, cntE, Binv);

    // y = bf16( Binv .* (S^T xb) )
    gather_bf<true, false, 0, CAP_E><<<(M_EDGES + 3) / 4, 256, 0, stream>>>(
        xb, cntE, listE, Binv, nullptr, y, nullptr, M_EDGES);
    // z = bf16( Dinv .* (S y) )
    gather_bf<true, false, 0, CAP_N><<<(N_NODES + 3) / 4, 256, 0, stream>>>(
        y, cntN, listN, Dinv, nullptr, z, nullptr, N_NODES);

    // hp = ( elu(z@W1+b1) ) @ W2, fused, in-place into z
    {
        int blocks = (N_NODES / 16 + 3) / 4;
        gemm_fused<<<blocks, 256, 0, stream>>>(z, pb1h, pb1l, b1, pb2h, pb2l, z, N_NODES);
    }

    // e = Binv .* (S^T hp): fp32 to output slot + bf16 copy (into y)
    gather_bf<true, false, 2, CAP_E><<<(M_EDGES + 3) / 4, 256, 0, stream>>>(
        z, cntE, listE, Binv, nullptr, y, e_out, M_EDGES);
    // out = Dinv .* (S e) + b2   (fp32)
    gather_bf<true, true, 1, CAP_N><<<(N_NODES + 3) / 4, 256, 0, stream>>>(
        y, cntN, listN, Dinv, b2, nullptr, out, N_NODES);
}

// Round 17
// 280.664 us; speedup vs baseline: 1.0008x; 1.0008x over previous
//
#include <hip/hip_runtime.h>
#include <stdint.h>

#define N_NODES 50000
#define M_EDGES 25000
#define NNZF    800000
#define F_IN    128
#define HID     256
#define F_OUT   128

#define CAP_N 64    // max node degree slot (Poisson(16): P>=64 ~ 1e-19/node)
#define CAP_E 96    // max edge cardinality slot (Poisson(32): negligible)

typedef __attribute__((ext_vector_type(8))) short bf16x8;
typedef __attribute__((ext_vector_type(4))) float f32x4;

__device__ __forceinline__ unsigned short bf16_rne(float f) {
    uint32_t b = __float_as_uint(f);
    b += 0x7FFF + ((b >> 16) & 1);
    return (unsigned short)(b >> 16);
}
__device__ __forceinline__ float bf16f(unsigned short h) {
    return __uint_as_float(((uint32_t)h) << 16);
}
__device__ __forceinline__ float bflo(unsigned u) { return __uint_as_float(u << 16); }
__device__ __forceinline__ float bfhi(unsigned u) { return __uint_as_float(u & 0xffff0000u); }

// ---------------- fp32 -> bf16 row conversion (x only) ----------------
__global__ void f32_to_bf16(const float* __restrict__ in, unsigned short* __restrict__ outp, int n) {
    int i = (blockIdx.x * blockDim.x + threadIdx.x) * 8;
    if (i >= n) return;
    float4 v0 = *reinterpret_cast<const float4*>(in + i);
    float4 v1 = *reinterpret_cast<const float4*>(in + i + 4);
    ushort4 o0, o1;
    o0.x = bf16_rne(v0.x); o0.y = bf16_rne(v0.y); o0.z = bf16_rne(v0.z); o0.w = bf16_rne(v0.w);
    o1.x = bf16_rne(v1.x); o1.y = bf16_rne(v1.y); o1.z = bf16_rne(v1.z); o1.w = bf16_rne(v1.w);
    *reinterpret_cast<ushort4*>(outp + i)     = o0;
    *reinterpret_cast<ushort4*>(outp + i + 4) = o1;
}

// ---------------- padded-CSR fill, XCD-binned + NON-TEMPORAL index loads ----------------
// The streamed nidx/eidx reads (6.4MB/pass) were evicting the partially-filled
// destination lines (2.8MB window) from the 4MB XCD L2 -> 10x write amplification
// (WRITE_SIZE 64.6MB vs ~6.5MB intrinsic). `nt` loads keep the dest lines resident
// so scattered 4B writes can combine into full lines before writeback.
__global__ __launch_bounds__(256) void fill_pad_nt(
    const int* __restrict__ nidx, const int* __restrict__ eidx,
    int* __restrict__ cntN, int* __restrict__ cntE,
    int* __restrict__ listN, int* __restrict__ listE, int nnz) {
    int p = blockIdx.x & 7;
    int blk = blockIdx.x >> 3;
    int nblk = gridDim.x >> 3;
    int stride = nblk * blockDim.x;
    for (int i = blk * blockDim.x + threadIdx.x; i < nnz; i += stride) {
        int nd = __builtin_nontemporal_load(nidx + i);
        int ed = __builtin_nontemporal_load(eidx + i);
        if (ed / 3125 == p) {                       // M_EDGES/8
            int s = atomicAdd(cntE + ed, 1);
            if (s < CAP_E) listE[ed * CAP_E + s] = nd;
        }
        if (nd / 6250 == p) {                       // N_NODES/8
            int s = atomicAdd(cntN + nd, 1);
            if (s < CAP_N) listN[nd * CAP_N + s] = ed;
        }
    }
}

// ---------------- inverse degree from counts ----------------
__global__ void inv_cnt2(const int* __restrict__ cntN, float* __restrict__ invN,
                         const int* __restrict__ cntE, float* __restrict__ invE) {
    int i = blockIdx.x * blockDim.x + threadIdx.x;
    if (i < N_NODES) { int v = cntN[i]; invN[i] = (v > 0) ? 1.0f / (float)v : 0.0f; }
    if (i < M_EDGES) { int v = cntE[i]; invE[i] = (v > 0) ? 1.0f / (float)v : 0.0f; }
}

// ---------------- gather segment-sum of 128-wide bf16 rows ----------------
// OUTMODE: 0 = bf16 only, 1 = fp32 only, 2 = both.
template<bool SCALE_DST, bool ADD_BIAS, int OUTMODE, int CAP>
__global__ __launch_bounds__(256) void gather_bf(
    const unsigned short* __restrict__ src, const int* __restrict__ cnt,
    const int* __restrict__ list, const float* __restrict__ dstscale,
    const float* __restrict__ bias,
    unsigned short* __restrict__ dstb, float* __restrict__ dstf, int rows) {
    int row = blockIdx.x * 4 + (threadIdx.x >> 6);
    if (row >= rows) return;
    int lane = threadIdx.x & 63;
    int half = lane >> 5;
    int l32 = lane & 31;
    const unsigned short* sp = src + l32 * 4;
    int c = cnt[row]; if (c > CAP) c = CAP;
    int s0 = row * CAP, s1 = s0 + c;

    float a0 = 0.f, a1 = 0.f, a2 = 0.f, a3 = 0.f;
    float c0 = 0.f, c1 = 0.f, c2 = 0.f, c3 = 0.f;
    int j = s0 + half;
    for (; j + 2 < s1; j += 4) {
        int i0 = list[j];
        int i1 = list[j + 2];
        uint2 u = *reinterpret_cast<const uint2*>(sp + (int64_t)i0 * 128);
        uint2 v = *reinterpret_cast<const uint2*>(sp + (int64_t)i1 * 128);
        a0 += bflo(u.x); a1 += bfhi(u.x); a2 += bflo(u.y); a3 += bfhi(u.y);
        c0 += bflo(v.x); c1 += bfhi(v.x); c2 += bflo(v.y); c3 += bfhi(v.y);
    }
    for (; j < s1; j += 2) {
        int i0 = list[j];
        uint2 u = *reinterpret_cast<const uint2*>(sp + (int64_t)i0 * 128);
        a0 += bflo(u.x); a1 += bfhi(u.x); a2 += bflo(u.y); a3 += bfhi(u.y);
    }
    a0 += c0; a1 += c1; a2 += c2; a3 += c3;

    a0 += __shfl_down(a0, 32, 64);
    a1 += __shfl_down(a1, 32, 64);
    a2 += __shfl_down(a2, 32, 64);
    a3 += __shfl_down(a3, 32, 64);

    if (half == 0) {
        if (SCALE_DST) {
            float sc = dstscale[row];
            a0 *= sc; a1 *= sc; a2 *= sc; a3 *= sc;
        }
        if (ADD_BIAS) {
            float4 bv = *reinterpret_cast<const float4*>(bias + l32 * 4);
            a0 += bv.x; a1 += bv.y; a2 += bv.z; a3 += bv.w;
        }
        if (OUTMODE == 1 || OUTMODE == 2) {
            float4 o; o.x = a0; o.y = a1; o.z = a2; o.w = a3;
            *reinterpret_cast<float4*>(dstf + (int64_t)row * 128 + l32 * 4) = o;
        }
        if (OUTMODE == 0 || OUTMODE == 2) {
            ushort4 ob;
            ob.x = bf16_rne(a0); ob.y = bf16_rne(a1);
            ob.z = bf16_rne(a2); ob.w = bf16_rne(a3);
            *reinterpret_cast<ushort4*>(dstb + (int64_t)row * 128 + l32 * 4) = ob;
        }
    }
}

// ---------------- pack W[K x Nc] into MFMA-fragment-ordered bf16 hi/lo ----------------
__global__ void pack_w(const float* __restrict__ W, short* __restrict__ Ph,
                       short* __restrict__ Pl, int K, int Nc) {
    int i = blockIdx.x * blockDim.x + threadIdx.x;
    if (i >= K * Nc) return;
    int k = i / Nc, n = i % Nc;
    float v = W[i];
    unsigned short h = bf16_rne(v);
    unsigned short lo = bf16_rne(v - bf16f(h));
    int KCH = K >> 5;
    int jt = n >> 4, c = k >> 5;
    int lane = (n & 15) | (((k >> 3) & 3) << 4);
    int j = k & 7;
    int64_t off = (((int64_t)(jt * KCH + c)) * 64 + lane) * 8 + j;
    Ph[off] = (short)h;
    Pl[off] = (short)lo;
}

// ---------------- FUSED MLP: hp = (elu(z@W1+b1)) @ W2, all bf16, h via per-wave LDS ----------------
__global__ __launch_bounds__(256) void gemm_fused(
    const unsigned short* __restrict__ A,
    const short* __restrict__ P1h, const short* __restrict__ P1l,
    const float* __restrict__ b1,
    const short* __restrict__ P2h, const short* __restrict__ P2l,
    unsigned short* __restrict__ Cout, int Mr) {
    __shared__ unsigned short ht[4][16][264];   // 33792 B
    int wid = threadIdx.x >> 6;
    int strip = blockIdx.x * 4 + wid;
    if (strip * 16 >= Mr) return;
    int l = threadIdx.x & 63;
    int lr = l & 15, lq = l >> 4;
    int arow = strip * 16 + lr;

    bf16x8 a1[4];
    const unsigned short* ap = A + (int64_t)arow * F_IN + lq * 8;
    #pragma unroll
    for (int c = 0; c < 4; ++c)
        a1[c] = *reinterpret_cast<const bf16x8*>(ap + c * 32);

    #pragma unroll
    for (int jt = 0; jt < HID / 16; ++jt) {
        f32x4 acc = {0.f, 0.f, 0.f, 0.f};
        #pragma unroll
        for (int c = 0; c < 4; ++c) {
            int64_t off = (((int64_t)(jt * 4 + c)) * 64 + l) * 8;
            bf16x8 bh = *reinterpret_cast<const bf16x8*>(P1h + off);
            bf16x8 bl = *reinterpret_cast<const bf16x8*>(P1l + off);
            acc = __builtin_amdgcn_mfma_f32_16x16x32_bf16(a1[c], bh, acc, 0, 0, 0);
            acc = __builtin_amdgcn_mfma_f32_16x16x32_bf16(a1[c], bl, acc, 0, 0, 0);
        }
        int col = jt * 16 + lr;
        float bv = b1[col];
        #pragma unroll
        for (int j = 0; j < 4; ++j) {
            float v = acc[j] + bv;
            v = (v > 0.f) ? v : expm1f(v);
            ht[wid][lq * 4 + j][col] = bf16_rne(v);
        }
    }

    bf16x8 a2[8];
    #pragma unroll
    for (int c = 0; c < 8; ++c)
        a2[c] = *reinterpret_cast<const bf16x8*>(&ht[wid][lr][lq * 8 + c * 32]);

    #pragma unroll
    for (int jt = 0; jt < F_OUT / 16; ++jt) {
        f32x4 acc = {0.f, 0.f, 0.f, 0.f};
        #pragma unroll
        for (int c = 0; c < 8; ++c) {
            int64_t off = (((int64_t)(jt * 8 + c)) * 64 + l) * 8;
            bf16x8 bh = *reinterpret_cast<const bf16x8*>(P2h + off);
            bf16x8 bl = *reinterpret_cast<const bf16x8*>(P2l + off);
            acc = __builtin_amdgcn_mfma_f32_16x16x32_bf16(a2[c], bh, acc, 0, 0, 0);
            acc = __builtin_amdgcn_mfma_f32_16x16x32_bf16(a2[c], bl, acc, 0, 0, 0);
        }
        int col = jt * 16 + lr;
        #pragma unroll
        for (int j = 0; j < 4; ++j)
            Cout[(int64_t)(strip * 16 + lq * 4 + j) * F_OUT + col] = bf16_rne(acc[j]);
    }
}

// ---------------- launch ----------------
extern "C" void kernel_launch(void* const* d_in, const int* in_sizes, int n_in,
                              void* d_out, int out_size, void* d_ws, size_t ws_size,
                              hipStream_t stream) {
    const float* x   = (const float*)d_in[0];
    const float* W1  = (const float*)d_in[1];
    const float* b1  = (const float*)d_in[2];
    const float* W2  = (const float*)d_in[3];
    const float* b2  = (const float*)d_in[4];
    const int*   nidx = (const int*)d_in[5];
    const int*   eidx = (const int*)d_in[6];

    float* out   = (float*)d_out;                      // [N, 128] fp32
    float* e_out = out + (size_t)N_NODES * F_OUT;      // [M, 128] fp32

    char* ws = (char*)d_ws;
    size_t off = 0;
    auto alloc = [&](size_t bytes) -> void* {
        void* p = ws + off;
        off += (bytes + 511) & ~(size_t)511;
        return p;
    };
    int* cntN    = (int*)alloc((size_t)(N_NODES + M_EDGES) * 4);   // contiguous; fill cursors == counts
    int* cntE    = cntN + N_NODES;
    float* Dinv  = (float*)alloc((size_t)N_NODES * 4);
    float* Binv  = (float*)alloc((size_t)M_EDGES * 4);
    int* listN   = (int*)alloc((size_t)N_NODES * CAP_N * 4);
    int* listE   = (int*)alloc((size_t)M_EDGES * CAP_E * 4);
    unsigned short* xb  = (unsigned short*)alloc((size_t)N_NODES * F_IN * 2);
    unsigned short* y   = (unsigned short*)alloc((size_t)M_EDGES * F_IN * 2);  // also ebf
    unsigned short* z   = (unsigned short*)alloc((size_t)N_NODES * F_IN * 2);  // also hp (in-place)
    short* pb1h  = (short*)alloc((size_t)F_IN * HID * 2);
    short* pb1l  = (short*)alloc((size_t)F_IN * HID * 2);
    short* pb2h  = (short*)alloc((size_t)HID * F_OUT * 2);
    short* pb2l  = (short*)alloc((size_t)HID * F_OUT * 2);

    hipMemsetAsync(cntN, 0, (size_t)(N_NODES + M_EDGES) * 4, stream);

    f32_to_bf16<<<(N_NODES * F_IN / 8 + 255) / 256, 256, 0, stream>>>(x, xb, N_NODES * F_IN);
    pack_w<<<(F_IN * HID + 255) / 256, 256, 0, stream>>>(W1, pb1h, pb1l, F_IN, HID);
    pack_w<<<(HID * F_OUT + 255) / 256, 256, 0, stream>>>(W2, pb2h, pb2l, HID, F_OUT);

    {
        int nblk_per_pass = (NNZF + 255) / 256;        // 3125
        fill_pad_nt<<<nblk_per_pass * 8, 256, 0, stream>>>(
            nidx, eidx, cntN, cntE, listN, listE, NNZF);
    }
    inv_cnt2<<<(N_NODES + 255) / 256, 256, 0, stream>>>(cntN, Dinv, cntE, Binv);

    // y = bf16( Binv .* (S^T xb) )
    gather_bf<true, false, 0, CAP_E><<<(M_EDGES + 3) / 4, 256, 0, stream>>>(
        xb, cntE, listE, Binv, nullptr, y, nullptr, M_EDGES);
    // z = bf16( Dinv .* (S y) )
    gather_bf<true, false, 0, CAP_N><<<(N_NODES + 3) / 4, 256, 0, stream>>>(
        y, cntN, listN, Dinv, nullptr, z, nullptr, N_NODES);

    // hp = ( elu(z@W1+b1) ) @ W2, fused, in-place into z
    {
        int blocks = (N_NODES / 16 + 3) / 4;
        gemm_fused<<<blocks, 256, 0, stream>>>(z, pb1h, pb1l, b1, pb2h, pb2l, z, N_NODES);
    }

    // e = Binv .* (S^T hp): fp32 to output slot + bf16 copy (into y)
    gather_bf<true, false, 2, CAP_E><<<(M_EDGES + 3) / 4, 256, 0, stream>>>(
        z, cntE, listE, Binv, nullptr, y, e_out, M_EDGES);
    // out = Dinv .* (S e) + b2   (fp32)
    gather_bf<true, true, 1, CAP_N><<<(N_NODES + 3) / 4, 256, 0, stream>>>(
        y, cntN, listN, Dinv, b2, nullptr, out, N_NODES);
}